// Round 4
// baseline (67797.217 us; speedup 1.0000x reference)
//
#include <hip/hip_runtime.h>
#include <math.h>

#define D   128
#define H   256
#define G4  1024   // 4*H
#define B   64
#define T   2048

__device__ __forceinline__ float fast_sig(float x) {
    return 1.0f / (1.0f + __expf(-x));
}
__device__ __forceinline__ float fast_tanh(float x) {
    float a = __expf(-2.0f * fabsf(x));      // in (0,1], never overflows
    float r = (1.0f - a) / (1.0f + a);
    return copysignf(r, x);
}
__device__ __forceinline__ void fma4(float4& s, float a, const float4 w) {
    s.x = fmaf(a, w.x, s.x);
    s.y = fmaf(a, w.y, s.y);
    s.z = fmaf(a, w.z, s.z);
    s.w = fmaf(a, w.w, s.w);
}

// ---------------------------------------------------------------------------
// Gate-interleave repack: Wp[k][4c+g] = W[k][g*H + c]  (g = i,f,g,o)
// rows 0..255 -> Whh, 256..383 -> Wih, 384 -> bias.
// After repack, gate column-quad 4c..4c+3 holds the 4 gate weights of
// h-column c, so one thread owns one h element end-to-end.
// ---------------------------------------------------------------------------
__global__ __launch_bounds__(256) void lstm_repack(
    const float* __restrict__ Wih, const float* __restrict__ Whh,
    const float* __restrict__ bias,
    float* __restrict__ Wihp, float* __restrict__ Whhp,
    float* __restrict__ biasp)
{
    const int r = blockIdx.x;
    const int c = threadIdx.x;
    if (r < H) {
        const float* src = Whh + (size_t)r * G4;
        float4 v = make_float4(src[c], src[H + c], src[2 * H + c], src[3 * H + c]);
        ((float4*)(Whhp + (size_t)r * G4))[c] = v;
    } else if (r < H + D) {
        const int d = r - H;
        const float* src = Wih + (size_t)d * G4;
        float4 v = make_float4(src[c], src[H + c], src[2 * H + c], src[3 * H + c]);
        ((float4*)(Wihp + (size_t)d * G4))[c] = v;
    } else {
        float4 v = make_float4(bias[c], bias[H + c], bias[2 * H + c], bias[3 * H + c]);
        ((float4*)biasp)[c] = v;
    }
}

// ---------------------------------------------------------------------------
// x-projection GEMM on the repacked W_ih: xp[t][b][:] = x[b][t][:] @ Wihp
// (output columns come out gate-interleaved, matching the scan).
// grid = (tn/16) * B blocks, 256 threads.
// ---------------------------------------------------------------------------
__global__ __launch_bounds__(256) void lstm_xproj(
    const float* __restrict__ x, const float* __restrict__ Wihp,
    float* __restrict__ xp, int t0, int tn)
{
    const int bi  = blockIdx.x % B;
    const int tt0 = (blockIdx.x / B) * 16;
    const int tid = threadIdx.x;

    __shared__ float4 xt[16][32];   // 16 timesteps x 128 floats

    const float4* src = (const float4*)(x + ((size_t)bi * T + (size_t)(t0 + tt0)) * D);
    #pragma unroll
    for (int r = tid; r < 16 * 32; r += 256) ((float4*)xt)[r] = src[r];
    __syncthreads();

    const float4* W4 = (const float4*)Wihp;   // [128][256] float4s
    float4 acc[16];
    #pragma unroll
    for (int tt = 0; tt < 16; ++tt) acc[tt] = make_float4(0.f, 0.f, 0.f, 0.f);

    for (int k0 = 0; k0 < 32; ++k0) {
        const int k = 4 * k0;
        float4 w0 = W4[(k + 0) * 256 + tid];
        float4 w1 = W4[(k + 1) * 256 + tid];
        float4 w2 = W4[(k + 2) * 256 + tid];
        float4 w3 = W4[(k + 3) * 256 + tid];
        #pragma unroll
        for (int tt = 0; tt < 16; ++tt) {
            float4 xv = xt[tt][k0];
            fma4(acc[tt], xv.x, w0);
            fma4(acc[tt], xv.y, w1);
            fma4(acc[tt], xv.z, w2);
            fma4(acc[tt], xv.w, w3);
        }
    }
    #pragma unroll
    for (int tt = 0; tt < 16; ++tt) {
        ((float4*)(xp + ((size_t)(tt0 + tt) * B + bi) * G4))[tid] = acc[tt];
    }
}

// ---------------------------------------------------------------------------
// Sequential LSTM scan v3: 64 WGs x 256 threads (1 wave/SIMD -> up to 512
// VGPRs for deep load pipelining; round-3's 1024-thread version was capped
// at 56 VGPRs -> serial L2 latency chain, VALUBusy 1.5%).
// Thread c owns h element c: acc float4 = {i,f,g,o} gates of column c.
// W_hh streamed from L2 via an explicit 2-stage register pipeline
// (16 float4 loads in flight = 64 KB/CU outstanding). h read from LDS as
// wave-uniform broadcast b128s. One barrier per step (double-buffered h).
// INLINE_X: also stream Wihp per step (fallback when d_ws can't hold xp).
// ---------------------------------------------------------------------------
template <bool INLINE_X>
__global__ __launch_bounds__(256, 1) void lstm_scan3(
    const float* __restrict__ x,  const float* __restrict__ xp,
    const float* __restrict__ Wihp, const float* __restrict__ Whhp,
    const float* __restrict__ biasp, const float* __restrict__ Wout,
    const float* __restrict__ bout,
    float* __restrict__ hstate, float* __restrict__ cstate,
    float* __restrict__ out, int t0, int tn)
{
    const int b = blockIdx.x;
    const int c = threadIdx.x;

    __shared__ float h_lds[2][H];
    __shared__ float xrow[2][D];
    __shared__ float red[4];

    const float4 bz = ((const float4*)biasp)[c];
    const float wout = Wout[c];

    float c_reg;
    if (t0 == 0) {
        h_lds[0][c] = 0.f;
        c_reg = 0.f;
    } else {
        h_lds[0][c] = hstate[b * H + c];
        c_reg       = cstate[b * H + c];
    }
    if (INLINE_X) {
        if (c < D / 4) {
            ((float4*)xrow[0])[c] =
                ((const float4*)(x + ((size_t)b * T + t0) * D))[c];
        }
    }
    __syncthreads();

    const float4* W   = (const float4*)Whhp;   // [256] rows x [256] float4
    const float4* Wx  = (const float4*)Wihp;   // [128] rows x [256] float4
    const float4* xp4 = (const float4*)xp;

    float4 xpn = make_float4(0.f, 0.f, 0.f, 0.f);
    if (!INLINE_X) xpn = xp4[((size_t)0 * B + b) * 256 + c];

    int cur = 0;
    for (int i = 0; i < tn; ++i) {
        float4 acc;
        if (!INLINE_X) {
            acc = make_float4(xpn.x + bz.x, xpn.y + bz.y, xpn.z + bz.z, xpn.w + bz.w);
            if (i + 1 < tn)   // issue next step's xp load early; used next iter
                xpn = xp4[((size_t)(i + 1) * B + b) * 256 + c];
        } else {
            acc = bz;
            // fold x @ W_ih: 128 rows, 8 chunks of 16, same pipeline shape
            const float* xr = xrow[i & 1];
            const float4* xr4 = (const float4*)xr;
            float4 wst[2][16];
            #pragma unroll
            for (int j = 0; j < 16; ++j) wst[0][j] = Wx[(size_t)j * 256 + c];
            #pragma unroll
            for (int k0 = 0; k0 < 8; ++k0) {
                const int cb = k0 & 1, nb = cb ^ 1;
                if (k0 < 7) {
                    #pragma unroll
                    for (int j = 0; j < 16; ++j)
                        wst[nb][j] = Wx[(size_t)((k0 + 1) * 16 + j) * 256 + c];
                }
                float4 q0 = xr4[k0 * 4 + 0], q1 = xr4[k0 * 4 + 1];
                float4 q2 = xr4[k0 * 4 + 2], q3 = xr4[k0 * 4 + 3];
                fma4(acc, q0.x, wst[cb][0]);  fma4(acc, q0.y, wst[cb][1]);
                fma4(acc, q0.z, wst[cb][2]);  fma4(acc, q0.w, wst[cb][3]);
                fma4(acc, q1.x, wst[cb][4]);  fma4(acc, q1.y, wst[cb][5]);
                fma4(acc, q1.z, wst[cb][6]);  fma4(acc, q1.w, wst[cb][7]);
                fma4(acc, q2.x, wst[cb][8]);  fma4(acc, q2.y, wst[cb][9]);
                fma4(acc, q2.z, wst[cb][10]); fma4(acc, q2.w, wst[cb][11]);
                fma4(acc, q3.x, wst[cb][12]); fma4(acc, q3.y, wst[cb][13]);
                fma4(acc, q3.z, wst[cb][14]); fma4(acc, q3.w, wst[cb][15]);
            }
            // prefetch next timestep's x row into the other LDS buffer
            if (c < D / 4 && (i + 1) < tn) {
                ((float4*)xrow[(i + 1) & 1])[c] =
                    ((const float4*)(x + ((size_t)b * T + (size_t)(t0 + i + 1)) * D))[c];
            }
        }

        // ---- h @ W_hh: 256 rows, 16 chunks of 16, 2-stage reg pipeline ----
        {
            const float4* h4 = (const float4*)h_lds[cur];
            float4 wst[2][16];
            #pragma unroll
            for (int j = 0; j < 16; ++j) wst[0][j] = W[(size_t)j * 256 + c];
            #pragma unroll
            for (int k0 = 0; k0 < 16; ++k0) {
                const int cb = k0 & 1, nb = cb ^ 1;
                if (k0 < 15) {
                    #pragma unroll
                    for (int j = 0; j < 16; ++j)
                        wst[nb][j] = W[(size_t)((k0 + 1) * 16 + j) * 256 + c];
                }
                float4 q0 = h4[k0 * 4 + 0], q1 = h4[k0 * 4 + 1];
                float4 q2 = h4[k0 * 4 + 2], q3 = h4[k0 * 4 + 3];
                fma4(acc, q0.x, wst[cb][0]);  fma4(acc, q0.y, wst[cb][1]);
                fma4(acc, q0.z, wst[cb][2]);  fma4(acc, q0.w, wst[cb][3]);
                fma4(acc, q1.x, wst[cb][4]);  fma4(acc, q1.y, wst[cb][5]);
                fma4(acc, q1.z, wst[cb][6]);  fma4(acc, q1.w, wst[cb][7]);
                fma4(acc, q2.x, wst[cb][8]);  fma4(acc, q2.y, wst[cb][9]);
                fma4(acc, q2.z, wst[cb][10]); fma4(acc, q2.w, wst[cb][11]);
                fma4(acc, q3.x, wst[cb][12]); fma4(acc, q3.y, wst[cb][13]);
                fma4(acc, q3.z, wst[cb][14]); fma4(acc, q3.w, wst[cb][15]);
            }
        }

        // ---- cell update: thread c owns element c, no reduction needed ----
        float ct = fast_sig(acc.y) * c_reg + fast_sig(acc.x) * fast_tanh(acc.z);
        float hn = fast_sig(acc.w) * fast_tanh(ct);
        c_reg = ct;
        const int nxt = cur ^ 1;
        h_lds[nxt][c] = hn;
        __syncthreads();    // h ready; also fences xrow prefetch buffer
        cur = nxt;
    }

    if (t0 + tn < T) {
        hstate[b * H + c] = h_lds[cur][c];
        cstate[b * H + c] = c_reg;
    } else {
        float p = h_lds[cur][c] * wout;
        #pragma unroll
        for (int m = 32; m >= 1; m >>= 1) p += __shfl_xor(p, m);
        if ((c & 63) == 0) red[c >> 6] = p;
        __syncthreads();
        if (c == 0) out[b] = red[0] + red[1] + red[2] + red[3] + bout[0];
    }
}

// ---------------------------------------------------------------------------
extern "C" void kernel_launch(void* const* d_in, const int* in_sizes, int n_in,
                              void* d_out, int out_size, void* d_ws, size_t ws_size,
                              hipStream_t stream)
{
    const float* x    = (const float*)d_in[0];
    const float* Wih  = (const float*)d_in[1];
    const float* Whh  = (const float*)d_in[2];
    const float* bias = (const float*)d_in[3];
    const float* Wout = (const float*)d_in[4];
    const float* bout = (const float*)d_in[5];
    float* out = (float*)d_out;

    // workspace layout: repacked weights + state + xp chunks
    char* p = (char*)d_ws;
    float* Whhp  = (float*)p;  p += (size_t)H * G4 * sizeof(float);   // 1 MB
    float* Wihp  = (float*)p;  p += (size_t)D * G4 * sizeof(float);   // 512 KB
    float* biasp = (float*)p;  p += (size_t)G4 * sizeof(float);       // 4 KB
    float* hs    = (float*)p;  p += (size_t)B * H * sizeof(float);
    float* cs    = (float*)p;  p += (size_t)B * H * sizeof(float);
    float* xp    = (float*)p;
    const size_t used = (size_t)(p - (char*)d_ws);
    const size_t rem  = (ws_size > used) ? ws_size - used : 0;

    int chunkT = 0;
    for (int ct = T; ct >= 16; ct >>= 1) {
        if ((size_t)ct * B * G4 * sizeof(float) <= rem) { chunkT = ct; break; }
    }

    lstm_repack<<<H + D + 1, 256, 0, stream>>>(Wih, Whh, bias, Wihp, Whhp, biasp);

    if (chunkT == 0) {
        // workspace too small for xp: fully fused fallback (streams Wihp too)
        lstm_scan3<true><<<B, 256, 0, stream>>>(
            x, nullptr, Wihp, Whhp, biasp, Wout, bout,
            hs, cs, out, 0, T);
    } else {
        for (int t0 = 0; t0 < T; t0 += chunkT) {
            lstm_xproj<<<dim3((chunkT / 16) * B), 256, 0, stream>>>(
                x, Wihp, xp, t0, chunkT);
            lstm_scan3<false><<<B, 256, 0, stream>>>(
                x, xp, Wihp, Whhp, biasp, Wout, bout,
                hs, cs, out, t0, chunkT);
        }
    }
}

// Round 8
// 51820.172 us; speedup vs baseline: 1.3083x; 1.3083x over previous
//
#include <hip/hip_runtime.h>
#include <hip/hip_bf16.h>
#include <math.h>

#define D   128
#define H   256
#define G4  1024   // 4*H
#define B   64
#define T   2048

__device__ __forceinline__ float fast_sig(float x) {
    return 1.0f / (1.0f + __expf(-x));
}
__device__ __forceinline__ float fast_tanh(float x) {
    float a = __expf(-2.0f * fabsf(x));      // in (0,1], never overflows
    float r = (1.0f - a) / (1.0f + a);
    return copysignf(r, x);
}
__device__ __forceinline__ void fma4(float4& s, float a, const float4 w) {
    s.x = fmaf(a, w.x, s.x);
    s.y = fmaf(a, w.y, s.y);
    s.z = fmaf(a, w.z, s.z);
    s.w = fmaf(a, w.w, s.w);
}

// bf16 helpers: exact bf16 bits -> fp32 (1 VALU op each)
__device__ __forceinline__ float bf_lo(unsigned v) {
    union { unsigned u; float f; } t; t.u = v << 16; return t.f;
}
__device__ __forceinline__ float bf_hi(unsigned v) {
    union { unsigned u; float f; } t; t.u = v & 0xFFFF0000u; return t.f;
}
// acc += h * {i,f,g,o} weights packed as uint2 (x: f<<16|i, y: o<<16|g)
__device__ __forceinline__ void fma_bf(float4& s, float a, const uint2 w) {
    s.x = fmaf(a, bf_lo(w.x), s.x);
    s.y = fmaf(a, bf_hi(w.x), s.y);
    s.z = fmaf(a, bf_lo(w.y), s.z);
    s.w = fmaf(a, bf_hi(w.y), s.w);
}
__device__ __forceinline__ unsigned short bfround(float x) {
    __hip_bfloat16 h = __float2bfloat16(x);   // RTN
    union { __hip_bfloat16 b; unsigned short u; } t; t.b = h; return t.u;
}

// ---------------------------------------------------------------------------
// Repack: W_hh -> gate-interleaved packed bf16 (uint2 per row per col-quad);
// W_ih -> gate-interleaved fp32 (for the xproj GEMM); bias -> float4/col.
// ---------------------------------------------------------------------------
__global__ __launch_bounds__(256) void lstm_repack(
    const float* __restrict__ Wih, const float* __restrict__ Whh,
    const float* __restrict__ bias,
    float* __restrict__ Wihp, uint2* __restrict__ Whhb,
    float* __restrict__ biasp)
{
    const int r = blockIdx.x;
    const int c = threadIdx.x;
    if (r < H) {
        const float* src = Whh + (size_t)r * G4;
        unsigned wi = bfround(src[c]);
        unsigned wf = bfround(src[H + c]);
        unsigned wg = bfround(src[2 * H + c]);
        unsigned wo = bfround(src[3 * H + c]);
        uint2 v;
        v.x = (wf << 16) | wi;
        v.y = (wo << 16) | wg;
        Whhb[(size_t)r * 256 + c] = v;
    } else if (r < H + D) {
        const int d = r - H;
        const float* src = Wih + (size_t)d * G4;
        float4 v = make_float4(src[c], src[H + c], src[2 * H + c], src[3 * H + c]);
        ((float4*)(Wihp + (size_t)d * G4))[c] = v;
    } else {
        float4 v = make_float4(bias[c], bias[H + c], bias[2 * H + c], bias[3 * H + c]);
        ((float4*)biasp)[c] = v;
    }
}

// ---------------------------------------------------------------------------
// x-projection GEMM on repacked W_ih: xp[t][b][:] = x[b][t][:] @ Wihp
// grid = (tn/16) * B blocks, 256 threads. (fp32, unchanged, verified)
// ---------------------------------------------------------------------------
__global__ __launch_bounds__(256) void lstm_xproj(
    const float* __restrict__ x, const float* __restrict__ Wihp,
    float* __restrict__ xp, int t0, int tn)
{
    const int bi  = blockIdx.x % B;
    const int tt0 = (blockIdx.x / B) * 16;
    const int tid = threadIdx.x;

    __shared__ float4 xt[16][32];   // 16 timesteps x 128 floats

    const float4* src = (const float4*)(x + ((size_t)bi * T + (size_t)(t0 + tt0)) * D);
    #pragma unroll
    for (int r = tid; r < 16 * 32; r += 256) ((float4*)xt)[r] = src[r];
    __syncthreads();

    const float4* W4 = (const float4*)Wihp;   // [128][256] float4s
    float4 acc[16];
    #pragma unroll
    for (int tt = 0; tt < 16; ++tt) acc[tt] = make_float4(0.f, 0.f, 0.f, 0.f);

    for (int k0 = 0; k0 < 32; ++k0) {
        const int k = 4 * k0;
        float4 w0 = W4[(k + 0) * 256 + tid];
        float4 w1 = W4[(k + 1) * 256 + tid];
        float4 w2 = W4[(k + 2) * 256 + tid];
        float4 w3 = W4[(k + 3) * 256 + tid];
        #pragma unroll
        for (int tt = 0; tt < 16; ++tt) {
            float4 xv = xt[tt][k0];
            fma4(acc[tt], xv.x, w0);
            fma4(acc[tt], xv.y, w1);
            fma4(acc[tt], xv.z, w2);
            fma4(acc[tt], xv.w, w3);
        }
    }
    #pragma unroll
    for (int tt = 0; tt < 16; ++tt) {
        ((float4*)(xp + ((size_t)(tt0 + tt) * B + bi) * G4))[tid] = acc[tt];
    }
}

// ---------------------------------------------------------------------------
// Sequential LSTM scan v7: v6 structure (64 WGs x 1024 threads, 16 waves =
// 4/SIMD TLP) with W_hh stored as packed bf16 -> half the per-step weight
// stream (1 MB -> 512 KB), fp32 accumulate. Thread (c = tid&255, ks = tid>>8)
// owns h-column c's gate quad over k-quarter [64ks, 64ks+64):
//   - W reads: lane-consecutive uint2 (512B/wave/instr), 2x8 reg dbuf
//   - h reads: wave-uniform LDS b128 broadcast (0 bank conflicts)
//   - 4-partial reduce via 16KB LDS, cell update on ks==0, 2 barriers/step
// ---------------------------------------------------------------------------
__global__ __launch_bounds__(1024, 4) void lstm_scan7(
    const float* __restrict__ xp, const uint2* __restrict__ Whhb,
    const float* __restrict__ biasp, const float* __restrict__ Wout,
    const float* __restrict__ bout,
    float* __restrict__ hstate, float* __restrict__ cstate,
    float* __restrict__ out, int t0, int tn)
{
    const int b   = blockIdx.x;
    const int tid = threadIdx.x;
    const int c   = tid & 255;
    const int ks  = tid >> 8;

    __shared__ __align__(16) float hbuf[2][H];
    __shared__ float4 part[4][H];      // 16 KB partial-sum exchange
    __shared__ float red[4];

    float c_reg = 0.f;
    float4 bz = make_float4(0.f, 0.f, 0.f, 0.f);
    if (ks == 0) {
        bz = ((const float4*)biasp)[c];
        if (t0 == 0) {
            hbuf[0][c] = 0.f;
            c_reg = 0.f;
        } else {
            hbuf[0][c] = hstate[b * H + c];
            c_reg      = cstate[b * H + c];
        }
    }
    __syncthreads();

    const float4* xp4 = (const float4*)xp;

    float4 xpn = make_float4(0.f, 0.f, 0.f, 0.f);
    if (ks == 0) xpn = xp4[((size_t)0 * B + b) * 256 + c];

    const int rbase = 64 * ks;                 // this thread's first W row
    int cur = 0;
    for (int i = 0; i < tn; ++i) {
        float4 acc;
        if (ks == 0) {
            acc = make_float4(xpn.x + bz.x, xpn.y + bz.y,
                              xpn.z + bz.z, xpn.w + bz.w);
            if (i + 1 < tn)    // prefetch next step's xp row
                xpn = xp4[((size_t)(i + 1) * B + b) * 256 + c];
        } else {
            acc = make_float4(0.f, 0.f, 0.f, 0.f);
        }

        // ---- partial h @ W_hh over rows [rbase, rbase+64), 2x8 reg dbuf ----
        {
            const float4* hq = (const float4*)(hbuf[cur] + rbase); // wave-uniform
            uint2 wst[2][8];
            #pragma unroll
            for (int jj = 0; jj < 8; ++jj)
                wst[0][jj] = Whhb[(size_t)(rbase + jj) * 256 + c];
            #pragma unroll
            for (int j0 = 0; j0 < 8; ++j0) {
                const int cb = j0 & 1, nb = cb ^ 1;
                if (j0 < 7) {
                    #pragma unroll
                    for (int jj = 0; jj < 8; ++jj)
                        wst[nb][jj] =
                            Whhb[(size_t)(rbase + (j0 + 1) * 8 + jj) * 256 + c];
                }
                float4 h0 = hq[j0 * 2 + 0];
                float4 h1 = hq[j0 * 2 + 1];
                fma_bf(acc, h0.x, wst[cb][0]); fma_bf(acc, h0.y, wst[cb][1]);
                fma_bf(acc, h0.z, wst[cb][2]); fma_bf(acc, h0.w, wst[cb][3]);
                fma_bf(acc, h1.x, wst[cb][4]); fma_bf(acc, h1.y, wst[cb][5]);
                fma_bf(acc, h1.z, wst[cb][6]); fma_bf(acc, h1.w, wst[cb][7]);
            }
        }

        part[ks][c] = acc;
        __syncthreads();   // partials ready

        if (ks == 0) {
            float4 p1 = part[1][c], p2 = part[2][c], p3 = part[3][c];
            float gi = acc.x + p1.x + p2.x + p3.x;
            float gf = acc.y + p1.y + p2.y + p3.y;
            float gg = acc.z + p1.z + p2.z + p3.z;
            float go = acc.w + p1.w + p2.w + p3.w;
            float ct = fast_sig(gf) * c_reg + fast_sig(gi) * fast_tanh(gg);
            float hn = fast_sig(go) * fast_tanh(ct);
            c_reg = ct;
            hbuf[cur ^ 1][c] = hn;
        }
        __syncthreads();   // h ready for next step
        cur ^= 1;
    }

    if (t0 + tn < T) {
        if (ks == 0) {
            hstate[b * H + c] = hbuf[cur][c];
            cstate[b * H + c] = c_reg;
        }
    } else {
        if (tid < H) {
            float p = hbuf[cur][tid] * Wout[tid];
            #pragma unroll
            for (int m = 32; m >= 1; m >>= 1) p += __shfl_xor(p, m);
            if ((tid & 63) == 0) red[tid >> 6] = p;
        }
        __syncthreads();
        if (tid == 0) out[b] = red[0] + red[1] + red[2] + red[3] + bout[0];
    }
}

// ---------------------------------------------------------------------------
// Fallback (workspace too small): round-3-style fused fp32 scan (proven).
// ---------------------------------------------------------------------------
__global__ __launch_bounds__(1024) void lstm_scan_fused(
    const float* __restrict__ x, const float* __restrict__ Wih,
    const float* __restrict__ Whh, const float* __restrict__ bias,
    const float* __restrict__ Wout, const float* __restrict__ bout,
    float* __restrict__ out)
{
    const int b   = blockIdx.x;
    const int tid = threadIdx.x;
    const int c4  = tid >> 2;
    const int ks  = tid & 3;

    __shared__ float h_lds[H];
    __shared__ float gates[G4];
    __shared__ float xrow[2][D];
    __shared__ float red[4];

    float c_reg = 0.f, bi_ = 0.f, bf_ = 0.f, bg_ = 0.f, bo_ = 0.f;
    if (tid < H) {
        h_lds[tid] = 0.f;
        bi_ = bias[tid];       bf_ = bias[H + tid];
        bg_ = bias[2 * H + tid]; bo_ = bias[3 * H + tid];
    }
    if (tid < D / 4)
        ((float4*)xrow[0])[tid] = ((const float4*)(x + (size_t)b * T * D))[tid];
    __syncthreads();

    const float4* Whh4 = (const float4*)Whh;
    const float4* Wih4 = (const float4*)Wih;
    const float4* h4   = (const float4*)h_lds;

    for (int i = 0; i < T; ++i) {
        float4 s = make_float4(0.f, 0.f, 0.f, 0.f);
        const float* xr = xrow[i & 1];
        for (int k0 = 0; k0 < 8; ++k0) {
            const int k = 32 * ks + 4 * k0;
            float4 xv = *(const float4*)&xr[k];
            fma4(s, xv.x, Wih4[(k + 0) * 256 + c4]);
            fma4(s, xv.y, Wih4[(k + 1) * 256 + c4]);
            fma4(s, xv.z, Wih4[(k + 2) * 256 + c4]);
            fma4(s, xv.w, Wih4[(k + 3) * 256 + c4]);
        }
        if (tid < 32 && (i + 1) < T)
            ((float4*)xrow[(i + 1) & 1])[tid] =
                ((const float4*)(x + ((size_t)b * T + i + 1) * D))[tid];
        #pragma unroll 4
        for (int k0 = 0; k0 < 16; ++k0) {
            const int kb = 16 * ks + k0;
            float4 hv = h4[kb];
            const int k = 4 * kb;
            fma4(s, hv.x, Whh4[(k + 0) * 256 + c4]);
            fma4(s, hv.y, Whh4[(k + 1) * 256 + c4]);
            fma4(s, hv.z, Whh4[(k + 2) * 256 + c4]);
            fma4(s, hv.w, Whh4[(k + 3) * 256 + c4]);
        }
        s.x += __shfl_xor(s.x, 1); s.x += __shfl_xor(s.x, 2);
        s.y += __shfl_xor(s.y, 1); s.y += __shfl_xor(s.y, 2);
        s.z += __shfl_xor(s.z, 1); s.z += __shfl_xor(s.z, 2);
        s.w += __shfl_xor(s.w, 1); s.w += __shfl_xor(s.w, 2);
        if (ks == 0) ((float4*)gates)[c4] = s;
        __syncthreads();
        if (tid < H) {
            float gi = gates[tid] + bi_, gf = gates[H + tid] + bf_;
            float gg = gates[2 * H + tid] + bg_, go = gates[3 * H + tid] + bo_;
            c_reg = fast_sig(gf) * c_reg + fast_sig(gi) * fast_tanh(gg);
            h_lds[tid] = fast_sig(go) * fast_tanh(c_reg);
        }
        __syncthreads();
    }
    if (tid < H) {
        float p = h_lds[tid] * Wout[tid];
        #pragma unroll
        for (int m = 32; m >= 1; m >>= 1) p += __shfl_xor(p, m);
        if ((tid & 63) == 0) red[tid >> 6] = p;
    }
    __syncthreads();
    if (tid == 0) out[b] = red[0] + red[1] + red[2] + red[3] + bout[0];
}

// ---------------------------------------------------------------------------
extern "C" void kernel_launch(void* const* d_in, const int* in_sizes, int n_in,
                              void* d_out, int out_size, void* d_ws, size_t ws_size,
                              hipStream_t stream)
{
    const float* x    = (const float*)d_in[0];
    const float* Wih  = (const float*)d_in[1];
    const float* Whh  = (const float*)d_in[2];
    const float* bias = (const float*)d_in[3];
    const float* Wout = (const float*)d_in[4];
    const float* bout = (const float*)d_in[5];
    float* out = (float*)d_out;

    // workspace layout: packed bf16 Whh + fp32 Wih/bias + state + xp chunk
    char* p = (char*)d_ws;
    uint2* Whhb  = (uint2*)p;  p += (size_t)H * 256 * sizeof(uint2);  // 512 KB
    float* Wihp  = (float*)p;  p += (size_t)D * G4 * sizeof(float);   // 512 KB
    float* biasp = (float*)p;  p += (size_t)G4 * sizeof(float);       // 4 KB
    float* hs    = (float*)p;  p += (size_t)B * H * sizeof(float);
    float* cs    = (float*)p;  p += (size_t)B * H * sizeof(float);
    float* xp    = (float*)p;
    const size_t used = (size_t)(p - (char*)d_ws);
    const size_t rem  = (ws_size > used) ? ws_size - used : 0;

    int chunkT = 0;
    for (int ct = T; ct >= 16; ct >>= 1) {
        if ((size_t)ct * B * G4 * sizeof(float) <= rem) { chunkT = ct; break; }
    }

    if (chunkT == 0) {
        lstm_scan_fused<<<B, 1024, 0, stream>>>(
            x, Wih, Whh, bias, Wout, bout, out);
        return;
    }

    lstm_repack<<<H + D + 1, 256, 0, stream>>>(Wih, Whh, bias, Wihp, Whhb, biasp);

    for (int t0 = 0; t0 < T; t0 += chunkT) {
        lstm_xproj<<<dim3((chunkT / 16) * B), 256, 0, stream>>>(
            x, Wihp, xp, t0, chunkT);
        lstm_scan7<<<B, 1024, 0, stream>>>(
            xp, Whhb, biasp, Wout, bout,
            hs, cs, out, t0, chunkT);
    }
}